// Round 7
// baseline (437.125 us; speedup 1.0000x reference)
//
#include <hip/hip_runtime.h>
#include <cmath>

#define SLEN 2048

typedef __bf16 bf16x8 __attribute__((ext_vector_type(8)));
typedef float  f32x4  __attribute__((ext_vector_type(4)));

__device__ inline void gld16(const void* g, void* l) {
    __builtin_amdgcn_global_load_lds(
        (const __attribute__((address_space(1))) void*)(uintptr_t)g,
        (__attribute__((address_space(3))) void*)(unsigned)(uintptr_t)l, 16, 0, 0);
}

// ---------------------------------------------------------------------------
// One-launch fp32->bf16 convert of all 9 inputs (segment table by value).
// ---------------------------------------------------------------------------
struct CvArgs {
    const float* src[9];
    __bf16*      dst[9];
    long         cum[10];
};
__global__ __launch_bounds__(256)
void convert_all(CvArgs a) {
    long i8 = ((long)blockIdx.x * 256 + threadIdx.x) * 8;
    if (i8 >= a.cum[9]) return;
    int s = 0;
#pragma unroll
    for (int k = 1; k < 9; k++) if (i8 >= a.cum[k]) s = k;
    long loc = i8 - a.cum[s];
    const float* sp = a.src[s] + loc;
    float4 u0 = *(const float4*)(sp);
    float4 u1 = *(const float4*)(sp + 4);
    bf16x8 o;
    o[0] = (__bf16)u0.x; o[1] = (__bf16)u0.y; o[2] = (__bf16)u0.z; o[3] = (__bf16)u0.w;
    o[4] = (__bf16)u1.x; o[5] = (__bf16)u1.y; o[6] = (__bf16)u1.z; o[7] = (__bf16)u1.w;
    *(bf16x8*)(a.dst[s] + loc) = o;
}

// ---------------------------------------------------------------------------
// NT GEMM, 128x128x64 tiles, 4 waves, global_load_lds + XOR-swizzled LDS.
// Modes: 2 fp32 out; 8 down-proj merged (+k-rope tile); 9 up-Q merged
// (scaled, +q-rope tiles); 10 up-KV merged (+V transpose).
// ---------------------------------------------------------------------------
struct Outs { __bf16* a; __bf16* b; __bf16* c; float* f; };

__global__ __launch_bounds__(256, 2)
void gemm_nt(const __bf16* __restrict__ A, const __bf16* __restrict__ B,
             Outs o, const int* __restrict__ positions,
             int M, int N, int K, int mode, float scale) {
    __shared__ __bf16 As[128 * 64];
    __shared__ __bf16 Bs[128 * 64];
    int tid = threadIdx.x;
    int wave = tid >> 6, lane = tid & 63;
    int lane15 = lane & 15, quad = lane >> 4;
    int ri = lane >> 3, ci = lane & 7;
    int cg = ci ^ ri;
    int m0 = blockIdx.x * 128, n0 = blockIdx.y * 128;
    int wm = (wave & 1) * 64, wn = (wave >> 1) * 64;
    f32x4 acc[4][4] = {};

    for (int k0 = 0; k0 < K; k0 += 64) {
#pragma unroll
        for (int t = 0; t < 4; t++) {
            int rr = wave * 32 + t * 8;
            int r = rr + ri;
            gld16(A + (size_t)(m0 + r) * K + k0 + cg * 8, As + rr * 64);
            int br = n0 + r; if (br > N - 1) br = N - 1;
            gld16(B + (size_t)br * K + k0 + cg * 8, Bs + rr * 64);
        }
        __syncthreads();
#pragma unroll
        for (int kk = 0; kk < 64; kk += 32) {
            int jb = kk >> 3;
            bf16x8 af[4], bfr[4];
#pragma unroll
            for (int mt = 0; mt < 4; mt++) {
                int rA = wm + mt * 16 + lane15;
                af[mt] = *(bf16x8*)(As + rA * 64 + (((jb + quad) ^ (rA & 7)) << 3));
            }
#pragma unroll
            for (int nt = 0; nt < 4; nt++) {
                int rB = wn + nt * 16 + lane15;
                bfr[nt] = *(bf16x8*)(Bs + rB * 64 + (((jb + quad) ^ (rB & 7)) << 3));
            }
#pragma unroll
            for (int mt = 0; mt < 4; mt++)
#pragma unroll
                for (int nt = 0; nt < 4; nt++)
                    acc[mt][nt] = __builtin_amdgcn_mfma_f32_16x16x32_bf16(
                        af[mt], bfr[nt], acc[mt][nt], 0, 0, 0);
        }
        __syncthreads();
    }

    const float KLOG = 13.287712379549449f / 32.0f;  // log2(10000)/32

    if (mode == 8 && n0 == 2048) {                     // k-rope + broadcast
        if (wn == 0) {
#pragma unroll
            for (int mt = 0; mt < 4; mt++) {
                int row = m0 + wm + mt * 16 + quad * 4;
#pragma unroll
                for (int nt = 0; nt < 2; nt++) {
                    int i = nt * 16 + lane15;
                    float inv = exp2f(-(float)i * KLOG);
#pragma unroll
                    for (int r = 0; r < 4; r++) {
                        int tok = row + r;
                        float p = (float)positions[tok & (SLEN - 1)];
                        float sn, cs; sincosf(p * inv, &sn, &cs);
                        float t1 = acc[mt][nt][r], t2 = acc[mt][nt + 2][r];
                        float rot1 = t1 * cs - t2 * sn;
                        float rot2 = t2 * cs + t1 * sn;
                        size_t ob = (size_t)tok * 3072 + 128;
#pragma unroll
                        for (int hh = 0; hh < 16; hh++) {
                            o.c[ob + hh * 192 + i]      = (__bf16)rot1;
                            o.c[ob + hh * 192 + 32 + i] = (__bf16)rot2;
                        }
                    }
                }
            }
        }
        return;
    }
    if (mode == 9 && n0 >= 2048) {                     // q-rope (scaled)
        int hh = (n0 + wn - 2048) >> 6;
#pragma unroll
        for (int mt = 0; mt < 4; mt++) {
            int row = m0 + wm + mt * 16 + quad * 4;
#pragma unroll
            for (int nt = 0; nt < 2; nt++) {
                int i = nt * 16 + lane15;
                float inv = exp2f(-(float)i * KLOG);
#pragma unroll
                for (int r = 0; r < 4; r++) {
                    int tok = row + r;
                    float p = (float)positions[tok & (SLEN - 1)];
                    float sn, cs; sincosf(p * inv, &sn, &cs);
                    float t1 = acc[mt][nt][r], t2 = acc[mt][nt + 2][r];
                    size_t ob = (size_t)tok * 3072 + hh * 192 + 128;
                    o.a[ob + i]      = (__bf16)((t1 * cs - t2 * sn) * scale);
                    o.a[ob + 32 + i] = (__bf16)((t2 * cs + t1 * sn) * scale);
                }
            }
        }
        return;
    }

#pragma unroll
    for (int mt = 0; mt < 4; mt++) {
        int row = m0 + wm + mt * 16 + quad * 4;
#pragma unroll
        for (int nt = 0; nt < 4; nt++) {
            int col = n0 + wn + nt * 16 + lane15;
            if (col < N) {
#pragma unroll
                for (int r = 0; r < 4; r++) {
                    float v = acc[mt][nt][r];
                    size_t rw = (size_t)(row + r);
                    if (mode == 2) {
                        o.f[rw * N + col] = v;
                    } else if (mode == 8) {
                        if (col < 1536) o.a[rw * 1536 + col] = (__bf16)v;
                        else            o.b[rw * 512 + col - 1536] = (__bf16)v;
                    } else if (mode == 9) {
                        o.a[rw * 3072 + (col >> 7) * 192 + (col & 127)] =
                            (__bf16)(v * scale);
                    } else {  // 10
                        if (col < 2048)
                            o.a[rw * 3072 + (col >> 7) * 192 + (col & 127)] = (__bf16)v;
                        else {
                            int d = col - 2048;
                            o.b[((size_t)d * 2 + (rw >> 11)) * 2048 + (rw & 2047)] = (__bf16)v;
                        }
                    }
                }
            }
        }
    }
}

// ---------------------------------------------------------------------------
// Causal flash attention with load-balanced work items.
// Per (h,b): 24 items, cost-descending (LPT): qt>=8 split into 2 j-segments
// (emit unnormalized bf16 O + fp32 m,l partials); qt<8 computed directly.
// Q-tile 128 (4 waves x 32 rows), K/V-tile 64, threshold-max softmax,
// row-sums via ones-MFMA, all LDS XOR-swizzled + global_load_lds staged.
// ---------------------------------------------------------------------------
__constant__ int QT_TAB[24] = {15,15,7,14,14,6,13,13,12,12,5,11,11,10,10,4,9,9,8,8,3,2,1,0};
__constant__ int SG_TAB[24] = {0,1,-1,0,1,-1,0,1,0,1,-1,0,1,0,1,-1,0,1,0,1,-1,-1,-1,-1};

__global__ __launch_bounds__(256, 2)
void mla_attn(const __bf16* __restrict__ Q, const __bf16* __restrict__ K,
              const __bf16* __restrict__ Vt, __bf16* __restrict__ O,
              __bf16* __restrict__ po, float* __restrict__ ml) {
    __shared__ __bf16 Ks[64 * 192];
    __shared__ __bf16 Vs[128 * 64];
    __shared__ __bf16 Ps[4][32][72];
    int tid = threadIdx.x, wave = tid >> 6, lane = tid & 63;
    int lane15 = lane & 15, quad = lane >> 4;
    int h = blockIdx.y, b = blockIdx.z;
    int item = blockIdx.x;
    int qt = QT_TAB[item], sg = SG_TAB[item];
    int q0 = qt * 128;
    int ib = (sg == 1) ? qt + 1 : 0;
    int ie = (sg == 0) ? qt + 1 : 2 * qt + 2;
    const __bf16* Qb  = Q + (size_t)b * SLEN * 3072 + h * 192;
    const __bf16* Kb  = K + (size_t)b * SLEN * 3072 + h * 192;
    const __bf16* vtb = Vt + ((size_t)(h * 128) * 2 + b) * 2048;

    bf16x8 qf[2][6];
#pragma unroll
    for (int mt = 0; mt < 2; mt++) {
        int qrow = q0 + wave * 32 + mt * 16 + lane15;
#pragma unroll
        for (int kk = 0; kk < 6; kk++)
            qf[mt][kk] = *(const bf16x8*)(Qb + (size_t)qrow * 3072 + kk * 32 + quad * 8);
    }
    bf16x8 ones;
#pragma unroll
    for (int e = 0; e < 8; e++) ones[e] = (__bf16)1.0f;

    f32x4 o_acc[2][8] = {};
    float m_i[2][4], l_i[2][4];
#pragma unroll
    for (int mt = 0; mt < 2; mt++)
#pragma unroll
        for (int r = 0; r < 4; r++) { m_i[mt][r] = -3.0e38f; l_i[mt][r] = 0.0f; }

    for (int ji = ib; ji < ie; ji++) {
        int j0 = ji * 64;
#pragma unroll
        for (int t = 0; t < 6; t++) {
            int sb = (wave * 6 + t) * 64;
            int slot = sb + lane;
            int r = slot / 24;
            int c = slot - r * 24;
            int cgk = (c & ~7) | ((c & 7) ^ (r & 7));
            gld16(Kb + (size_t)(j0 + r) * 3072 + cgk * 8, Ks + sb * 8);
        }
#pragma unroll
        for (int t = 0; t < 4; t++) {
            int sb = (wave * 4 + t) * 64;
            int slot = sb + lane;
            int r = slot >> 3, c = slot & 7;
            gld16(vtb + (size_t)r * 4096 + j0 + (c ^ (r & 7)) * 8, Vs + sb * 8);
        }
        __syncthreads();

        f32x4 acc[2][4] = {};
#pragma unroll
        for (int kk = 0; kk < 6; kk++) {
#pragma unroll
            for (int nt = 0; nt < 4; nt++) {
                int n = nt * 16 + lane15;
                int j = kk * 4 + quad;
                int cl = (j & ~7) | ((j & 7) ^ (n & 7));
                bf16x8 kf = *(bf16x8*)(Ks + n * 192 + cl * 8);
#pragma unroll
                for (int mt = 0; mt < 2; mt++)
                    acc[mt][nt] = __builtin_amdgcn_mfma_f32_16x16x32_bf16(
                        qf[mt][kk], kf, acc[mt][nt], 0, 0, 0);
            }
        }

        if (j0 >= q0) {  // causal mask (only last two tiles; always in seg1)
#pragma unroll
            for (int mt = 0; mt < 2; mt++) {
                int rowg = q0 + wave * 32 + mt * 16 + quad * 4;
#pragma unroll
                for (int nt = 0; nt < 4; nt++) {
                    int colg = j0 + nt * 16 + lane15;
#pragma unroll
                    for (int r = 0; r < 4; r++)
                        if (colg > rowg + r) acc[mt][nt][r] = -3.0e38f;
                }
            }
        }

        float mx[2][4];
        bool need = false;
#pragma unroll
        for (int mt = 0; mt < 2; mt++)
#pragma unroll
            for (int r = 0; r < 4; r++) {
                float v = fmaxf(fmaxf(acc[mt][0][r], acc[mt][1][r]),
                                fmaxf(acc[mt][2][r], acc[mt][3][r]));
                mx[mt][r] = v;
                need = need || (v > m_i[mt][r] + 24.0f);
            }
        if (__any(need)) {
#pragma unroll
            for (int mt = 0; mt < 2; mt++)
#pragma unroll
                for (int r = 0; r < 4; r++) {
                    float v = mx[mt][r];
#pragma unroll
                    for (int d = 8; d >= 1; d >>= 1) v = fmaxf(v, __shfl_xor(v, d));
                    float mn = fmaxf(m_i[mt][r], v);
                    float alpha = exp2f(m_i[mt][r] - mn);
                    m_i[mt][r] = mn;
                    l_i[mt][r] *= alpha;
#pragma unroll
                    for (int nt = 0; nt < 8; nt++) o_acc[mt][nt][r] *= alpha;
                }
        }

#pragma unroll
        for (int mt = 0; mt < 2; mt++)
#pragma unroll
            for (int r = 0; r < 4; r++)
#pragma unroll
                for (int nt = 0; nt < 4; nt++) {
                    float pp = exp2f(acc[mt][nt][r] - m_i[mt][r]);
                    Ps[wave][mt * 16 + quad * 4 + r][nt * 16 + lane15] = (__bf16)pp;
                }

        f32x4 rs[2] = {};
#pragma unroll
        for (int ks = 0; ks < 2; ks++) {
            bf16x8 pf[2];
#pragma unroll
            for (int mt = 0; mt < 2; mt++)
                pf[mt] = *(bf16x8*)(&Ps[wave][mt * 16 + lane15][ks * 32 + quad * 8]);
#pragma unroll
            for (int nt = 0; nt < 8; nt++) {
                int nn = nt * 16 + lane15;
                int j = ks * 4 + quad;
                bf16x8 vf = *(bf16x8*)(Vs + nn * 64 + (j ^ (nn & 7)) * 8);
#pragma unroll
                for (int mt = 0; mt < 2; mt++)
                    o_acc[mt][nt] = __builtin_amdgcn_mfma_f32_16x16x32_bf16(
                        pf[mt], vf, o_acc[mt][nt], 0, 0, 0);
            }
#pragma unroll
            for (int mt = 0; mt < 2; mt++)
                rs[mt] = __builtin_amdgcn_mfma_f32_16x16x32_bf16(
                    pf[mt], ones, rs[mt], 0, 0, 0);
        }
#pragma unroll
        for (int mt = 0; mt < 2; mt++)
#pragma unroll
            for (int r = 0; r < 4; r++) l_i[mt][r] += rs[mt][r];
        __syncthreads();
    }

    if (sg < 0) {   // direct tile: normalize and write
        int tokb = b * SLEN + q0 + wave * 32 + quad * 4;
#pragma unroll
        for (int mt = 0; mt < 2; mt++)
#pragma unroll
            for (int r = 0; r < 4; r++) {
                float inv_l = 1.0f / l_i[mt][r];
                int tok = tokb + mt * 16 + r;
#pragma unroll
                for (int nt = 0; nt < 8; nt++)
                    O[(size_t)tok * 2048 + h * 128 + nt * 16 + lane15] =
                        (__bf16)(o_acc[mt][nt][r] * inv_l);
            }
    } else {        // segment: emit unnormalized partial + (m,l)
        int tseg = (((b * 16 + h) * 8) + (qt - 8)) * 2 + sg;
        __bf16* pb = po + (size_t)tseg * 16384;
        float*  mb = ml + (size_t)tseg * 256;
#pragma unroll
        for (int mt = 0; mt < 2; mt++)
#pragma unroll
            for (int r = 0; r < 4; r++) {
                int row = wave * 32 + mt * 16 + quad * 4 + r;
#pragma unroll
                for (int nt = 0; nt < 8; nt++)
                    pb[(size_t)row * 128 + nt * 16 + lane15] = (__bf16)o_acc[mt][nt][r];
                if (lane15 == 0) {
                    mb[row * 2]     = m_i[mt][r];
                    mb[row * 2 + 1] = l_i[mt][r];
                }
            }
    }
}

// ---------------------------------------------------------------------------
// Merge the two segments of each split tile (qt>=8).
// ---------------------------------------------------------------------------
__global__ __launch_bounds__(256)
void attn_merge(const __bf16* __restrict__ po, const float* __restrict__ ml,
                __bf16* __restrict__ O) {
    int t = blockIdx.x;                 // 0..255: ((b*16+h)*8 + qt-8)
    int qti = t & 7, h = (t >> 3) & 15, b = t >> 7;
    int row = threadIdx.x >> 1;
    int cb = (threadIdx.x & 1) * 64;
    int tok = b * SLEN + (8 + qti) * 128 + row;
    size_t s0 = (size_t)(t * 2) * 16384 + (size_t)row * 128 + cb;
    size_t s1 = s0 + 16384;
    float2 a0 = *(const float2*)(ml + (size_t)(t * 2) * 256 + row * 2);
    float2 a1 = *(const float2*)(ml + (size_t)(t * 2 + 1) * 256 + row * 2);
    float mM = fmaxf(a0.x, a1.x);
    float w0 = exp2f(a0.x - mM), w1 = exp2f(a1.x - mM);
    float inv = 1.0f / (w0 * a0.y + w1 * a1.y);
    w0 *= inv; w1 *= inv;
#pragma unroll
    for (int c = 0; c < 8; c++) {
        bf16x8 v0 = *(const bf16x8*)(po + s0 + c * 8);
        bf16x8 v1 = *(const bf16x8*)(po + s1 + c * 8);
        bf16x8 o;
#pragma unroll
        for (int e = 0; e < 8; e++)
            o[e] = (__bf16)(w0 * (float)v0[e] + w1 * (float)v1[e]);
        *(bf16x8*)(O + (size_t)tok * 2048 + h * 128 + cb + c * 8) = o;
    }
}

// ---------------------------------------------------------------------------
extern "C" void kernel_launch(void* const* d_in, const int* in_sizes, int n_in,
                              void* d_out, int out_size, void* d_ws, size_t ws_size,
                              hipStream_t stream) {
    (void)in_sizes; (void)n_in; (void)out_size; (void)ws_size;
    const int* pos = (const int*)d_in[1];
    float* out = (float*)d_out;

    char* ws = (char*)d_ws;
    size_t off = 0;
    auto alloc = [&](size_t bytes) {
        char* p = ws + off;
        off += (bytes + 255) & ~(size_t)255;
        return p;
    };
    __bf16* x_bf  = (__bf16*)alloc(8388608ull * 2);  // dead after G1 -> po overlay
    __bf16* Wcat1 = (__bf16*)alloc(4325376ull * 2);
    __bf16* Wcat2 = (__bf16*)alloc(4718592ull * 2);
    __bf16* Wcat3 = (__bf16*)alloc(4194304ull * 2);
    __bf16* Wob   = (__bf16*)alloc(4194304ull * 2);
    __bf16* c_q   = (__bf16*)alloc(4096ull * 1536 * 2);
    __bf16* c_kv  = (__bf16*)alloc(4096ull * 512 * 2);
    __bf16* v_t   = (__bf16*)alloc(4096ull * 2048 * 2);
    __bf16* q_all = (__bf16*)alloc(4096ull * 3072 * 2);
    __bf16* k_all = (__bf16*)alloc(4096ull * 3072 * 2);
    float*  ml    = (float*)alloc(512ull * 256 * 4);
    __bf16* attn_o = (__bf16*)c_q;   // overlays c_q+c_kv (exactly 16.78 MB)
    __bf16* po     = x_bf;           // 512 segs x 32 KB = 16.78 MB, overlays x_bf

    const float scale_l2 = 1.4426950408889634f / sqrtf(192.0f);
    dim3 blk(256);

    CvArgs cv;
    cv.src[0] = (const float*)d_in[0]; cv.dst[0] = x_bf;
    cv.src[1] = (const float*)d_in[2]; cv.dst[1] = Wcat1;
    cv.src[2] = (const float*)d_in[5]; cv.dst[2] = Wcat1 + 3145728;
    cv.src[3] = (const float*)d_in[8]; cv.dst[3] = Wcat1 + 4194304;
    cv.src[4] = (const float*)d_in[3]; cv.dst[4] = Wcat2;
    cv.src[5] = (const float*)d_in[4]; cv.dst[5] = Wcat2 + 3145728;
    cv.src[6] = (const float*)d_in[6]; cv.dst[6] = Wcat3;
    cv.src[7] = (const float*)d_in[7]; cv.dst[7] = Wcat3 + 1048576;
    cv.src[8] = (const float*)d_in[9]; cv.dst[8] = Wob;
    long ns[9] = {8388608, 3145728, 1048576, 131072, 3145728, 1572864,
                  1048576, 1048576, 4194304};
    cv.cum[0] = 0;
    for (int i = 0; i < 9; i++) cv.cum[i + 1] = cv.cum[i] + ns[i];
    convert_all<<<dim3((unsigned)(cv.cum[9] / 2048)), blk, 0, stream>>>(cv);

    Outs o1 = { c_q, c_kv, k_all, nullptr };
    gemm_nt<<<dim3(32, 17), blk, 0, stream>>>(x_bf, Wcat1, o1, pos, 4096, 2112, 2048, 8, 1.0f);
    Outs o2 = { q_all, nullptr, nullptr, nullptr };
    gemm_nt<<<dim3(32, 24), blk, 0, stream>>>(c_q, Wcat2, o2, pos, 4096, 3072, 1536, 9, scale_l2);
    Outs o3 = { k_all, v_t, nullptr, nullptr };
    gemm_nt<<<dim3(32, 32), blk, 0, stream>>>(c_kv, Wcat3, o3, pos, 4096, 4096, 512, 10, 1.0f);
    mla_attn<<<dim3(24, 16, 2), blk, 0, stream>>>(q_all, k_all, v_t, attn_o, po, ml);
    attn_merge<<<dim3(256), blk, 0, stream>>>(po, ml, attn_o);
    Outs o4 = { nullptr, nullptr, nullptr, out };
    gemm_nt<<<dim3(32, 16), blk, 0, stream>>>(attn_o, Wob, o4, pos, 4096, 2048, 2048, 2, 1.0f);
}